// Round 2
// baseline (685.177 us; speedup 1.0000x reference)
//
#include <hip/hip_runtime.h>
#include <math.h>

// Fused MLP 256->64->16->4 + global softmax over flattened [B*4].
//
// Layout: lane = row. Each lane accumulates all 64 h1 columns in VGPRs
// (acc[64]); w1 rows are wave-uniform -> s_load into SGPRs, so the hot loop
// is pure v_fmac(acc[c], s_w, v_x) with per-lane contiguous x loads.
// K is split in half across wave pairs (waves 2g / 2g+1) to double the wave
// count (4096 waves = 16/CU) so SMEM latency is covered; partial z1 combined
// via a small padded LDS tile. Layers 2/3 are per-lane scalar fp32 (tiny).
// exp written unnormalized + atomic sum; norm_kernel scales by 1/S.

#define ROWS_PER_BLOCK 128           // 2 row-groups x 64 rows
#define NBLOCKS (131072 / ROWS_PER_BLOCK)   // 1024

__global__ __launch_bounds__(256, 4)
void mlp_kernel(const float* __restrict__ x, const float* __restrict__ w1,
                const float* __restrict__ b1, const float* __restrict__ w2,
                const float* __restrict__ b2, const float* __restrict__ w3,
                const float* __restrict__ b3, float* __restrict__ out,
                float* __restrict__ wsum)
{
    // 2 groups x 64 rows x stride 68 floats (16B-aligned, min-phase b128)
    __shared__ float part[2][64][68];      // 34816 B -> 4 blocks/CU fits 160K

    const int tid   = threadIdx.x;
    const int lane  = tid & 63;
    const int wid   = tid >> 6;
    const int g     = wid >> 1;            // row-group 0/1
    const int khalf = wid & 1;             // K-half 0/1

    const int row = blockIdx.x * ROWS_PER_BLOCK + g * 64 + lane;
    const float* xr  = x + (size_t)row * 256 + khalf * 128;
    const float* w1h = w1 + (size_t)khalf * 128 * 64;

    float acc[64];
#pragma unroll
    for (int c = 0; c < 64; ++c) acc[c] = 0.0f;

    // K-half = 128, in 8 chunks of 16
    for (int kc = 0; kc < 8; ++kc) {
        const float4 xv0 = *(const float4*)(xr + kc * 16 + 0);
        const float4 xv1 = *(const float4*)(xr + kc * 16 + 4);
        const float4 xv2 = *(const float4*)(xr + kc * 16 + 8);
        const float4 xv3 = *(const float4*)(xr + kc * 16 + 12);
        const float xk[16] = { xv0.x, xv0.y, xv0.z, xv0.w,
                               xv1.x, xv1.y, xv1.z, xv1.w,
                               xv2.x, xv2.y, xv2.z, xv2.w,
                               xv3.x, xv3.y, xv3.z, xv3.w };
#pragma unroll
        for (int k = 0; k < 16; ++k) {
            const float xv = xk[k];
            const float* wrow = w1h + (size_t)(kc * 16 + k) * 64;  // wave-uniform
#pragma unroll
            for (int c = 0; c < 64; ++c)
                acc[c] = fmaf(xv, wrow[c], acc[c]);
        }
    }

    // combine K-halves through LDS
    if (khalf == 1) {
#pragma unroll
        for (int c = 0; c < 64; c += 4) {
            *(float4*)&part[g][lane][c] =
                make_float4(acc[c], acc[c + 1], acc[c + 2], acc[c + 3]);
        }
    }
    __syncthreads();
    if (khalf == 1) return;   // no further barriers

    // z1 = accA + accB + b1, relu (in place in acc)
#pragma unroll
    for (int c = 0; c < 64; c += 4) {
        const float4 p = *(const float4*)&part[g][lane][c];
        acc[c + 0] = fmaxf(acc[c + 0] + p.x + b1[c + 0], 0.0f);
        acc[c + 1] = fmaxf(acc[c + 1] + p.y + b1[c + 1], 0.0f);
        acc[c + 2] = fmaxf(acc[c + 2] + p.z + b1[c + 2], 0.0f);
        acc[c + 3] = fmaxf(acc[c + 3] + p.w + b1[c + 3], 0.0f);
    }

    // layer 2: z2[j] = b2[j] + sum_c h[c]*w2[c][j]   (w2 wave-uniform)
    float z2[16];
#pragma unroll
    for (int j = 0; j < 16; ++j) z2[j] = b2[j];
#pragma unroll
    for (int c = 0; c < 64; ++c) {
        const float hv = acc[c];
#pragma unroll
        for (int j = 0; j < 16; ++j)
            z2[j] = fmaf(hv, w2[c * 16 + j], z2[j]);
    }
#pragma unroll
    for (int j = 0; j < 16; ++j) z2[j] = tanhf(z2[j]);

    // layer 3 + exp
    float l0 = b3[0], l1 = b3[1], l2 = b3[2], l3 = b3[3];
#pragma unroll
    for (int j = 0; j < 16; ++j) {
        const float t = z2[j];
        l0 = fmaf(t, w3[j * 4 + 0], l0);
        l1 = fmaf(t, w3[j * 4 + 1], l1);
        l2 = fmaf(t, w3[j * 4 + 2], l2);
        l3 = fmaf(t, w3[j * 4 + 3], l3);
    }
    const float e0 = expf(l0), e1 = expf(l1), e2 = expf(l2), e3 = expf(l3);
    *(float4*)&out[(size_t)row * 4] = make_float4(e0, e1, e2, e3);

    // wave sum of exp -> one atomic per (even) wave
    float s = e0 + e1 + e2 + e3;
#pragma unroll
    for (int off = 1; off < 64; off <<= 1) s += __shfl_xor(s, off);
    if (lane == 0) atomicAdd(wsum, s);
}

__global__ __launch_bounds__(256)
void norm_kernel(float4* __restrict__ out, const float* __restrict__ wsum, int n4)
{
    const int i = blockIdx.x * 256 + threadIdx.x;
    if (i < n4) {
        const float inv = 1.0f / *wsum;
        float4 v = out[i];
        v.x *= inv; v.y *= inv; v.z *= inv; v.w *= inv;
        out[i] = v;
    }
}

extern "C" void kernel_launch(void* const* d_in, const int* in_sizes, int n_in,
                              void* d_out, int out_size, void* d_ws, size_t ws_size,
                              hipStream_t stream) {
    (void)in_sizes; (void)n_in; (void)ws_size;
    const float* x  = (const float*)d_in[0];
    const float* w1 = (const float*)d_in[1];
    const float* b1 = (const float*)d_in[2];
    const float* w2 = (const float*)d_in[3];
    const float* b2 = (const float*)d_in[4];
    const float* w3 = (const float*)d_in[5];
    const float* b3 = (const float*)d_in[6];
    float* out  = (float*)d_out;
    float* wsum = (float*)d_ws;

    hipMemsetAsync(wsum, 0, sizeof(float), stream);
    mlp_kernel<<<NBLOCKS, 256, 0, stream>>>(x, w1, b1, w2, b2, w3, b3, out, wsum);
    const int n4 = out_size >> 2;
    norm_kernel<<<(n4 + 255) / 256, 256, 0, stream>>>((float4*)out, wsum, n4);
}

// Round 3
// 265.052 us; speedup vs baseline: 2.5851x; 2.5851x over previous
//
#include <hip/hip_runtime.h>
#include <math.h>

// Fused MLP 256->64->16->4 + global softmax over flattened [B*4].
//
// Block = 256 threads = 4 waves, covering 64 rows (lane = row).
// Each wave owns a 16-column chunk of h1 -> acc[16]/lane (no spill).
// x tile (64 rows x 128 k, pad +1) staged in LDS in two K-passes; compute
// read xs[lane*129+k] hits bank (lane+k)%32 = 2-way = free.
// w1 chunk pointer forced wave-uniform (readfirstlane) -> s_load weights;
// hot loop = ds_read_b32 + 16 v_fmac per k. x-tile LDS reused for h1 stash
// (stride 65 -> conflict-free) feeding layers 2/3 per-wave (16 rows/wave,
// 4 lanes/row, quad shuffle-reduce). exp written unnormalized + 1 atomic
// per block; norm_kernel scales by 1/S.

#define NBLOCKS (131072 / 64)   // 2048

__global__ __launch_bounds__(256, 4)
void mlp_kernel(const float* __restrict__ x, const float* __restrict__ w1,
                const float* __restrict__ b1, const float* __restrict__ w2,
                const float* __restrict__ b2, const float* __restrict__ w3,
                const float* __restrict__ b3, float* __restrict__ out,
                float* __restrict__ wsum)
{
    __shared__ float xs[64 * 129];   // 33024 B; reused as hs[64*65] after barrier
    __shared__ float ws2[64 * 16];   // 4096 B
    __shared__ float ws3[16 * 4];    // 256 B
    __shared__ float bsum[4];
    // total ~37.6 KB -> 4 blocks/CU -> 16 waves/CU

    const int tid  = threadIdx.x;
    const int lane = tid & 63;
    const int wid  = tid >> 6;
    const int c0   = __builtin_amdgcn_readfirstlane(wid * 16);  // force SGPR
    const int row0 = blockIdx.x * 64;

    // stage w2/w3 (before the pass-0 barrier)
    for (int i = tid; i < 64 * 16; i += 256) ws2[i] = w2[i];
    if (tid < 64) ws3[tid] = w3[tid];

    float acc[16];
#pragma unroll
    for (int j = 0; j < 16; ++j) acc[j] = 0.0f;

    for (int p = 0; p < 2; ++p) {
        __syncthreads();   // readers of previous tile done (and w2 staged)
#pragma unroll
        for (int i = 0; i < 8; ++i) {
            const int idx = i * 256 + tid;
            const int r = idx >> 5;        // 0..63
            const int f = idx & 31;        // float4 index within 128-float half-row
            const float4 v = *(const float4*)(x + (size_t)(row0 + r) * 256 + p * 128 + f * 4);
            float* d = &xs[r * 129 + f * 4];
            d[0] = v.x; d[1] = v.y; d[2] = v.z; d[3] = v.w;
        }
        __syncthreads();

        const float* w1p = w1 + (size_t)p * 128 * 64 + c0;
        const float* xrow = &xs[lane * 129];
#pragma unroll 4
        for (int k = 0; k < 128; ++k) {
            const float xv = xrow[k];                 // ds_read_b32, conflict-free
            const float* wr = w1p + (size_t)k * 64;   // wave-uniform -> s_load
#pragma unroll
            for (int j = 0; j < 16; ++j)
                acc[j] = fmaf(xv, wr[j], acc[j]);
        }
    }
    __syncthreads();   // all waves done reading xs; safe to reuse as hs

    // bias + relu -> h stash, hs[row][c], stride 65 (bank = row+c, free)
    float* hs = xs;
#pragma unroll
    for (int j = 0; j < 16; ++j)
        hs[lane * 65 + c0 + j] = fmaxf(acc[j] + b1[c0 + j], 0.0f);
    __syncthreads();

    // layers 2/3: wave w -> rows 16w..16w+15; 4 lanes per row (q = lane&3)
    const int r2  = wid * 16 + (lane >> 2);  // row within block
    const int q   = lane & 3;

    float z2[4];
#pragma unroll
    for (int t = 0; t < 4; ++t) z2[t] = b2[4 * t + q];
#pragma unroll 8
    for (int c = 0; c < 64; ++c) {
        const float hv = hs[r2 * 65 + c];    // 16 rows x 4-lane broadcast: free
#pragma unroll
        for (int t = 0; t < 4; ++t)
            z2[t] = fmaf(hv, ws2[c * 16 + 4 * t + q], z2[t]);
    }

    float lg[4] = {0.0f, 0.0f, 0.0f, 0.0f};
#pragma unroll
    for (int t = 0; t < 4; ++t) {
        const float th = tanhf(z2[t]);
        const int j = 4 * t + q;
#pragma unroll
        for (int o = 0; o < 4; ++o)
            lg[o] = fmaf(th, ws3[j * 4 + o], lg[o]);
    }
    // quad reduce (lanes 4r..4r+3 hold partials of the same row)
#pragma unroll
    for (int o = 0; o < 4; ++o) {
        lg[o] += __shfl_xor(lg[o], 1);
        lg[o] += __shfl_xor(lg[o], 2);
        lg[o] = expf(lg[o] + b3[o]);   // |logit| small: no overflow
    }
    if (q == 0)
        *(float4*)&out[(size_t)(row0 + r2) * 4] =
            make_float4(lg[0], lg[1], lg[2], lg[3]);

    // block sum of exp (each row counted 4x -> *0.25)
    float s = (lg[0] + lg[1] + lg[2] + lg[3]) * 0.25f;
#pragma unroll
    for (int off = 1; off < 64; off <<= 1) s += __shfl_xor(s, off);
    if (lane == 0) bsum[wid] = s;
    __syncthreads();
    if (tid == 0) atomicAdd(wsum, bsum[0] + bsum[1] + bsum[2] + bsum[3]);
}

__global__ __launch_bounds__(256)
void norm_kernel(float4* __restrict__ out, const float* __restrict__ wsum, int n4)
{
    const int i = blockIdx.x * 256 + threadIdx.x;
    if (i < n4) {
        const float inv = 1.0f / *wsum;
        float4 v = out[i];
        v.x *= inv; v.y *= inv; v.z *= inv; v.w *= inv;
        out[i] = v;
    }
}

extern "C" void kernel_launch(void* const* d_in, const int* in_sizes, int n_in,
                              void* d_out, int out_size, void* d_ws, size_t ws_size,
                              hipStream_t stream) {
    (void)in_sizes; (void)n_in; (void)ws_size;
    const float* x  = (const float*)d_in[0];
    const float* w1 = (const float*)d_in[1];
    const float* b1 = (const float*)d_in[2];
    const float* w2 = (const float*)d_in[3];
    const float* b2 = (const float*)d_in[4];
    const float* w3 = (const float*)d_in[5];
    const float* b3 = (const float*)d_in[6];
    float* out  = (float*)d_out;
    float* wsum = (float*)d_ws;

    hipMemsetAsync(wsum, 0, sizeof(float), stream);
    mlp_kernel<<<NBLOCKS, 256, 0, stream>>>(x, w1, b1, w2, b2, w3, b3, out, wsum);
    const int n4 = out_size >> 2;
    norm_kernel<<<(n4 + 255) / 256, 256, 0, stream>>>((float4*)out, wsum, n4);
}

// Round 5
// 217.971 us; speedup vs baseline: 3.1434x; 1.2160x over previous
//
#include <hip/hip_runtime.h>
#include <math.h>

// Fused MLP 256->64->16->4 + global softmax over flattened [B*4].
//
// Layer 1 via bf16 MFMA (16x16x32) with 3-term split precision:
//   x = xh + xl, w = wh + wl (bf16 each);  x*w ~= xh*wh + xl*wh + xh*wl
// (dropping xl*wl, rel ~2^-18; R4's 2-term concat dropped the 2^-9 cross
// terms -> 3.4e-3 absmax fail).
// w1' staged once per block in LDS as [n][k] bf16 hi+lo, k-stride 520
// (260 dw == 4 mod 32 -> uniform bank tiling for b128 frag reads).
// A-fragments loaded per-lane straight from global (coalesced, converted
// in-reg) -> no s_load / no x-LDS in the hot loop. Epilogue reuses the w1'
// LDS as h-stash (stride 68) for the layer-2/3 path (2 threads/row).
// exp written unnormalized + 1 atomic/block; norm_kernel scales by 1/S.

typedef __attribute__((ext_vector_type(8))) short bf16x8;  // 8 bf16 = 4 VGPRs
typedef __attribute__((ext_vector_type(4))) float f32x4;

#define WK 520   // k-stride in wlds (bf16 elems); 520*2B = 260 dw, 260%32==4
#define HS 68    // hs row stride (floats)
#define NBLOCKS 512   // 131072 rows / 256 rows per block

__device__ __forceinline__ short f2bf(float v) {   // fp32 -> bf16 bits, RNE
    unsigned u = __float_as_uint(v);
    unsigned r = (u + 0x7FFFu + ((u >> 16) & 1u)) >> 16;
    return (short)r;
}
__device__ __forceinline__ float bf2f(short s) {
    return __uint_as_float(((unsigned)(unsigned short)s) << 16);
}

__global__ __launch_bounds__(512, 4)
void mlp_kernel(const float* __restrict__ x, const float* __restrict__ w1,
                const float* __restrict__ b1, const float* __restrict__ w2,
                const float* __restrict__ b2, const float* __restrict__ w3,
                const float* __restrict__ b3, float* __restrict__ out,
                float* __restrict__ wsum)
{
    // union: wlds = 64*520*2 = 66560 B; hs = 256*68*4 = 69632 B
    __shared__ __align__(16) char smem[256 * HS * 4];
    __shared__ float ws2[64 * 16];
    __shared__ float ws3[64];
    __shared__ float bs1[64];
    __shared__ float bsum[8];
    short* wlds = (short*)smem;
    float* hs   = (float*)smem;

    const int tid  = threadIdx.x;
    const int lane = tid & 63;
    const int wid  = tid >> 6;    // 0..7
    const int quad = lane >> 4;   // 0..3
    const int m16  = lane & 15;

    // ---- stage small weights + w1 -> bf16 hi/lo in LDS ----
    for (int i = tid; i < 1024; i += 512) ws2[i] = w2[i];
    if (tid < 64) ws3[tid] = w3[tid];
    if (tid >= 64 && tid < 128) bs1[tid - 64] = b1[tid - 64];
    {
        const int n  = tid & 63;
        const int kb = (tid >> 6) * 4;
        for (int kk = kb; kk < 256; kk += 32) {
            const float v0 = w1[(size_t)(kk + 0) * 64 + n];
            const float v1 = w1[(size_t)(kk + 1) * 64 + n];
            const float v2 = w1[(size_t)(kk + 2) * 64 + n];
            const float v3 = w1[(size_t)(kk + 3) * 64 + n];
            short4 hi, lo;
            hi.x = f2bf(v0); lo.x = f2bf(v0 - bf2f(hi.x));
            hi.y = f2bf(v1); lo.y = f2bf(v1 - bf2f(hi.y));
            hi.z = f2bf(v2); lo.z = f2bf(v2 - bf2f(hi.z));
            hi.w = f2bf(v3); lo.w = f2bf(v3 - bf2f(hi.w));
            *(short4*)&wlds[n * WK + kk]       = hi;   // hi at k
            *(short4*)&wlds[n * WK + 256 + kk] = lo;   // lo at 256 + k
        }
    }
    __syncthreads();

    // ---- layer 1 MFMA: wave = 32 rows x 64 cols ----
    const int row0 = blockIdx.x * 256 + wid * 32;
    f32x4 acc[2][4];
#pragma unroll
    for (int mt = 0; mt < 2; ++mt)
#pragma unroll
        for (int t = 0; t < 4; ++t) acc[mt][t] = (f32x4)0.0f;

#pragma unroll 2
    for (int s = 0; s < 8; ++s) {      // fp32-K steps of 32
        bf16x8 bh[4], bl[4];
#pragma unroll
        for (int t = 0; t < 4; ++t) {  // B-frag: n = t*16+m16, k = quad*8+j
            const short* bp = &wlds[(t * 16 + m16) * WK + s * 32 + quad * 8];
            bh[t] = *(const bf16x8*)bp;
            bl[t] = *(const bf16x8*)(bp + 256);
        }
#pragma unroll
        for (int mt = 0; mt < 2; ++mt) {
            // A-frag: m = m16, k = quad*8+j  -> per-lane 32 B contiguous
            const float* xp = x + (size_t)(row0 + mt * 16 + m16) * 256
                                + s * 32 + quad * 8;
            const float4 v0 = *(const float4*)xp;
            const float4 v1 = *(const float4*)(xp + 4);
            const float f[8] = {v0.x, v0.y, v0.z, v0.w, v1.x, v1.y, v1.z, v1.w};
            bf16x8 ah, al;
#pragma unroll
            for (int j = 0; j < 8; ++j) {
                const short h = f2bf(f[j]);
                ah[j] = h;
                al[j] = f2bf(f[j] - bf2f(h));
            }
            // 3-term split: ah*bh + al*bh + ah*bl  (al*bl ~ 2^-18, dropped)
#pragma unroll
            for (int t = 0; t < 4; ++t)
                acc[mt][t] = __builtin_amdgcn_mfma_f32_16x16x32_bf16(
                    ah, bh[t], acc[mt][t], 0, 0, 0);
#pragma unroll
            for (int t = 0; t < 4; ++t)
                acc[mt][t] = __builtin_amdgcn_mfma_f32_16x16x32_bf16(
                    al, bh[t], acc[mt][t], 0, 0, 0);
#pragma unroll
            for (int t = 0; t < 4; ++t)
                acc[mt][t] = __builtin_amdgcn_mfma_f32_16x16x32_bf16(
                    ah, bl[t], acc[mt][t], 0, 0, 0);
        }
    }
    __syncthreads();   // all waves done reading wlds -> reuse as hs

    // ---- bias + relu -> h stash (C/D: n-col = lane&15, m-row = quad*4+r) ----
#pragma unroll
    for (int mt = 0; mt < 2; ++mt)
#pragma unroll
        for (int t = 0; t < 4; ++t) {
            const float bc = bs1[t * 16 + m16];
#pragma unroll
            for (int r = 0; r < 4; ++r) {
                const int rr = wid * 32 + mt * 16 + quad * 4 + r;
                hs[rr * HS + t * 16 + m16] = fmaxf(acc[mt][t][r] + bc, 0.0f);
            }
        }
    __syncthreads();

    // ---- layers 2/3: 2 threads per row, 8 z2-cols each ----
    const int r2 = tid >> 1;
    const int jq = (tid & 1) * 8;
    float z2[8];
#pragma unroll
    for (int jj = 0; jj < 8; ++jj) z2[jj] = b2[jq + jj];
#pragma unroll 4
    for (int c = 0; c < 64; c += 4) {
        const float4 h4 = *(const float4*)&hs[r2 * HS + c];
        const float hv[4] = {h4.x, h4.y, h4.z, h4.w};
#pragma unroll
        for (int i = 0; i < 4; ++i)
#pragma unroll
            for (int jj = 0; jj < 8; ++jj)
                z2[jj] = fmaf(hv[i], ws2[(c + i) * 16 + jq + jj], z2[jj]);
    }
    float l0 = 0.f, l1 = 0.f, l2 = 0.f, l3 = 0.f;
#pragma unroll
    for (int jj = 0; jj < 8; ++jj) {
        const float th = tanhf(z2[jj]);
        const int j = jq + jj;
        l0 = fmaf(th, ws3[j * 4 + 0], l0);
        l1 = fmaf(th, ws3[j * 4 + 1], l1);
        l2 = fmaf(th, ws3[j * 4 + 2], l2);
        l3 = fmaf(th, ws3[j * 4 + 3], l3);
    }
    l0 += __shfl_xor(l0, 1); l1 += __shfl_xor(l1, 1);
    l2 += __shfl_xor(l2, 1); l3 += __shfl_xor(l3, 1);

    float s = 0.0f;
    if ((tid & 1) == 0) {
        const float e0 = expf(l0 + b3[0]);
        const float e1 = expf(l1 + b3[1]);
        const float e2 = expf(l2 + b3[2]);
        const float e3 = expf(l3 + b3[3]);
        *(float4*)&out[(size_t)(blockIdx.x * 256 + r2) * 4] =
            make_float4(e0, e1, e2, e3);
        s = e0 + e1 + e2 + e3;
    }
#pragma unroll
    for (int off = 1; off < 64; off <<= 1) s += __shfl_xor(s, off);
    if (lane == 0) bsum[wid] = s;
    __syncthreads();
    if (tid == 0) {
        float tot = 0.0f;
#pragma unroll
        for (int i = 0; i < 8; ++i) tot += bsum[i];
        atomicAdd(wsum, tot);
    }
}

__global__ __launch_bounds__(256)
void norm_kernel(float4* __restrict__ out, const float* __restrict__ wsum, int n4)
{
    const int i = blockIdx.x * 256 + threadIdx.x;
    if (i < n4) {
        const float inv = 1.0f / *wsum;
        float4 v = out[i];
        v.x *= inv; v.y *= inv; v.z *= inv; v.w *= inv;
        out[i] = v;
    }
}

extern "C" void kernel_launch(void* const* d_in, const int* in_sizes, int n_in,
                              void* d_out, int out_size, void* d_ws, size_t ws_size,
                              hipStream_t stream) {
    (void)in_sizes; (void)n_in; (void)ws_size;
    const float* x  = (const float*)d_in[0];
    const float* w1 = (const float*)d_in[1];
    const float* b1 = (const float*)d_in[2];
    const float* w2 = (const float*)d_in[3];
    const float* b2 = (const float*)d_in[4];
    const float* w3 = (const float*)d_in[5];
    const float* b3 = (const float*)d_in[6];
    float* out  = (float*)d_out;
    float* wsum = (float*)d_ws;

    hipMemsetAsync(wsum, 0, sizeof(float), stream);
    mlp_kernel<<<NBLOCKS, 512, 0, stream>>>(x, w1, b1, w2, b2, w3, b3, out, wsum);
    const int n4 = out_size >> 2;
    norm_kernel<<<(n4 + 255) / 256, 256, 0, stream>>>((float4*)out, wsum, n4);
}

// Round 6
// 216.719 us; speedup vs baseline: 3.1616x; 1.0058x over previous
//
#include <hip/hip_runtime.h>
#include <hip/hip_bf16.h>
#include <math.h>

// Fused MLP 256->64->16->4 + global softmax over flattened [B*4].
//
// Layer 1 via bf16 MFMA (16x16x32), 3-term split precision:
//   x*w ~= xh*wh + xl*wh + xh*wl   (xl*wl ~2^-18 dropped; verified R5 7.6e-6)
// R6 changes vs R5 (structure identical otherwise):
//  - explicit software prefetch of next s-step's x float4s (hide ~900cyc HBM)
//  - packed v_cvt_pk_bf16_f32 converts via __float22bfloat162_rn
// w1' staged per block in LDS [n][k] bf16 hi+lo, k-stride 520 (260dw%32==4).
// Epilogue reuses w1' LDS as h-stash (stride 68), layer-2/3 2 threads/row.
// exp unnormalized + 1 atomic/block; norm_kernel scales by 1/S.

typedef __attribute__((ext_vector_type(8))) short bf16x8;  // 8 bf16 = 4 VGPRs
typedef __attribute__((ext_vector_type(4))) float f32x4;

#define WK 520
#define HS 68
#define NBLOCKS 512   // 131072 rows / 256 rows per block

__device__ __forceinline__ short f2bf(float v) {   // scalar fallback (staging)
    unsigned u = __float_as_uint(v);
    unsigned r = (u + 0x7FFFu + ((u >> 16) & 1u)) >> 16;
    return (short)r;
}
__device__ __forceinline__ float bf2f(short s) {
    return __uint_as_float(((unsigned)(unsigned short)s) << 16);
}

// 8 fp32 -> bf16 hi + lo fragments, packed converts
__device__ __forceinline__ void cvt8(const float4 v0, const float4 v1,
                                     bf16x8& ah, bf16x8& al)
{
    const float f[8] = {v0.x, v0.y, v0.z, v0.w, v1.x, v1.y, v1.z, v1.w};
    unsigned* ahp = (unsigned*)&ah;
    unsigned* alp = (unsigned*)&al;
#pragma unroll
    for (int p = 0; p < 4; ++p) {
        float2 fp = make_float2(f[2 * p], f[2 * p + 1]);
        __hip_bfloat162 h2 = __float22bfloat162_rn(fp);      // v_cvt_pk_bf16_f32
        float2 hf = __bfloat1622float2(h2);
        __hip_bfloat162 l2 =
            __float22bfloat162_rn(make_float2(fp.x - hf.x, fp.y - hf.y));
        union { __hip_bfloat162 b; unsigned u; } ch, cl;
        ch.b = h2; cl.b = l2;
        ahp[p] = ch.u;
        alp[p] = cl.u;
    }
}

__global__ __launch_bounds__(512, 4)
void mlp_kernel(const float* __restrict__ x, const float* __restrict__ w1,
                const float* __restrict__ b1, const float* __restrict__ w2,
                const float* __restrict__ b2, const float* __restrict__ w3,
                const float* __restrict__ b3, float* __restrict__ out,
                float* __restrict__ wsum)
{
    // union: wlds = 64*520*2 = 66560 B; hs = 256*68*4 = 69632 B
    __shared__ __align__(16) char smem[256 * HS * 4];
    __shared__ float ws2[64 * 16];
    __shared__ float ws3[64];
    __shared__ float bs1[64];
    __shared__ float bsum[8];
    short* wlds = (short*)smem;
    float* hs   = (float*)smem;

    const int tid  = threadIdx.x;
    const int lane = tid & 63;
    const int wid  = tid >> 6;    // 0..7
    const int quad = lane >> 4;   // 0..3
    const int m16  = lane & 15;

    // ---- stage small weights + w1 -> bf16 hi/lo in LDS ----
    for (int i = tid; i < 1024; i += 512) ws2[i] = w2[i];
    if (tid < 64) ws3[tid] = w3[tid];
    if (tid >= 64 && tid < 128) bs1[tid - 64] = b1[tid - 64];
    {
        const int n  = tid & 63;
        const int kb = (tid >> 6) * 4;
        for (int kk = kb; kk < 256; kk += 32) {
            const float v0 = w1[(size_t)(kk + 0) * 64 + n];
            const float v1 = w1[(size_t)(kk + 1) * 64 + n];
            const float v2 = w1[(size_t)(kk + 2) * 64 + n];
            const float v3 = w1[(size_t)(kk + 3) * 64 + n];
            short4 hi, lo;
            hi.x = f2bf(v0); lo.x = f2bf(v0 - bf2f(hi.x));
            hi.y = f2bf(v1); lo.y = f2bf(v1 - bf2f(hi.y));
            hi.z = f2bf(v2); lo.z = f2bf(v2 - bf2f(hi.z));
            hi.w = f2bf(v3); lo.w = f2bf(v3 - bf2f(hi.w));
            *(short4*)&wlds[n * WK + kk]       = hi;   // hi at k
            *(short4*)&wlds[n * WK + 256 + kk] = lo;   // lo at 256 + k
        }
    }
    __syncthreads();

    // ---- layer 1 MFMA: wave = 32 rows x 64 cols ----
    const int row0 = blockIdx.x * 256 + wid * 32;
    // per-lane x base: row = row0 + mt*16 + m16, col = s*32 + quad*8
    const float* xb0 = x + (size_t)(row0 + m16) * 256 + quad * 8;
    const float* xb1 = xb0 + 16 * 256;

    f32x4 acc[2][4];
#pragma unroll
    for (int mt = 0; mt < 2; ++mt)
#pragma unroll
        for (int t = 0; t < 4; ++t) acc[mt][t] = (f32x4)0.0f;

    // prefetch s=0
    float4 cur[4];
    cur[0] = *(const float4*)(xb0);
    cur[1] = *(const float4*)(xb0 + 4);
    cur[2] = *(const float4*)(xb1);
    cur[3] = *(const float4*)(xb1 + 4);

#pragma unroll
    for (int s = 0; s < 8; ++s) {
        float4 nxt[4];
        if (s < 7) {           // issue next-step loads FIRST (latency hiding)
            const int off = (s + 1) * 32;
            nxt[0] = *(const float4*)(xb0 + off);
            nxt[1] = *(const float4*)(xb0 + off + 4);
            nxt[2] = *(const float4*)(xb1 + off);
            nxt[3] = *(const float4*)(xb1 + off + 4);
        }
        bf16x8 bh[4], bl[4];
#pragma unroll
        for (int t = 0; t < 4; ++t) {  // B-frag: n = t*16+m16, k = quad*8+j
            const short* bp = &wlds[(t * 16 + m16) * WK + s * 32 + quad * 8];
            bh[t] = *(const bf16x8*)bp;
            bl[t] = *(const bf16x8*)(bp + 256);
        }
#pragma unroll
        for (int mt = 0; mt < 2; ++mt) {
            bf16x8 ah, al;
            cvt8(cur[mt * 2 + 0], cur[mt * 2 + 1], ah, al);
            // 3-term split: ah*bh + al*bh + ah*bl
#pragma unroll
            for (int t = 0; t < 4; ++t)
                acc[mt][t] = __builtin_amdgcn_mfma_f32_16x16x32_bf16(
                    ah, bh[t], acc[mt][t], 0, 0, 0);
#pragma unroll
            for (int t = 0; t < 4; ++t)
                acc[mt][t] = __builtin_amdgcn_mfma_f32_16x16x32_bf16(
                    al, bh[t], acc[mt][t], 0, 0, 0);
#pragma unroll
            for (int t = 0; t < 4; ++t)
                acc[mt][t] = __builtin_amdgcn_mfma_f32_16x16x32_bf16(
                    ah, bl[t], acc[mt][t], 0, 0, 0);
        }
#pragma unroll
        for (int i = 0; i < 4; ++i) cur[i] = nxt[i];
    }
    __syncthreads();   // all waves done reading wlds -> reuse as hs

    // ---- bias + relu -> h stash (C/D: col = t*16+m16, row = quad*4+r) ----
#pragma unroll
    for (int mt = 0; mt < 2; ++mt)
#pragma unroll
        for (int t = 0; t < 4; ++t) {
            const float bc = bs1[t * 16 + m16];
#pragma unroll
            for (int r = 0; r < 4; ++r) {
                const int rr = wid * 32 + mt * 16 + quad * 4 + r;
                hs[rr * HS + t * 16 + m16] = fmaxf(acc[mt][t][r] + bc, 0.0f);
            }
        }
    __syncthreads();

    // ---- layers 2/3: 2 threads per row, 8 z2-cols each ----
    const int r2 = tid >> 1;
    const int jq = (tid & 1) * 8;
    float z2[8];
#pragma unroll
    for (int jj = 0; jj < 8; ++jj) z2[jj] = b2[jq + jj];
#pragma unroll 4
    for (int c = 0; c < 64; c += 4) {
        const float4 h4 = *(const float4*)&hs[r2 * HS + c];
        const float hv[4] = {h4.x, h4.y, h4.z, h4.w};
#pragma unroll
        for (int i = 0; i < 4; ++i)
#pragma unroll
            for (int jj = 0; jj < 8; ++jj)
                z2[jj] = fmaf(hv[i], ws2[(c + i) * 16 + jq + jj], z2[jj]);
    }
    float l0 = 0.f, l1 = 0.f, l2 = 0.f, l3 = 0.f;
#pragma unroll
    for (int jj = 0; jj < 8; ++jj) {
        const float th = tanhf(z2[jj]);
        const int j = jq + jj;
        l0 = fmaf(th, ws3[j * 4 + 0], l0);
        l1 = fmaf(th, ws3[j * 4 + 1], l1);
        l2 = fmaf(th, ws3[j * 4 + 2], l2);
        l3 = fmaf(th, ws3[j * 4 + 3], l3);
    }
    l0 += __shfl_xor(l0, 1); l1 += __shfl_xor(l1, 1);
    l2 += __shfl_xor(l2, 1); l3 += __shfl_xor(l3, 1);

    float s = 0.0f;
    if ((tid & 1) == 0) {
        const float e0 = expf(l0 + b3[0]);
        const float e1 = expf(l1 + b3[1]);
        const float e2 = expf(l2 + b3[2]);
        const float e3 = expf(l3 + b3[3]);
        *(float4*)&out[(size_t)(blockIdx.x * 256 + r2) * 4] =
            make_float4(e0, e1, e2, e3);
        s = e0 + e1 + e2 + e3;
    }
#pragma unroll
    for (int off = 1; off < 64; off <<= 1) s += __shfl_xor(s, off);
    if (lane == 0) bsum[wid] = s;
    __syncthreads();
    if (tid == 0) {
        float tot = 0.0f;
#pragma unroll
        for (int i = 0; i < 8; ++i) tot += bsum[i];
        atomicAdd(wsum, tot);
    }
}

__global__ __launch_bounds__(256)
void norm_kernel(float4* __restrict__ out, const float* __restrict__ wsum, int n4)
{
    const int i = blockIdx.x * 256 + threadIdx.x;
    if (i < n4) {
        const float inv = 1.0f / *wsum;
        float4 v = out[i];
        v.x *= inv; v.y *= inv; v.z *= inv; v.w *= inv;
        out[i] = v;
    }
}

extern "C" void kernel_launch(void* const* d_in, const int* in_sizes, int n_in,
                              void* d_out, int out_size, void* d_ws, size_t ws_size,
                              hipStream_t stream) {
    (void)in_sizes; (void)n_in; (void)ws_size;
    const float* x  = (const float*)d_in[0];
    const float* w1 = (const float*)d_in[1];
    const float* b1 = (const float*)d_in[2];
    const float* w2 = (const float*)d_in[3];
    const float* b2 = (const float*)d_in[4];
    const float* w3 = (const float*)d_in[5];
    const float* b3 = (const float*)d_in[6];
    float* out  = (float*)d_out;
    float* wsum = (float*)d_ws;

    hipMemsetAsync(wsum, 0, sizeof(float), stream);
    mlp_kernel<<<NBLOCKS, 512, 0, stream>>>(x, w1, b1, w2, b2, w3, b3, out, wsum);
    const int n4 = out_size >> 2;
    norm_kernel<<<(n4 + 255) / 256, 256, 0, stream>>>((float4*)out, wsum, n4);
}